// Round 1
// baseline (28.149 us; speedup 1.0000x reference)
//
#include <hip/hip_runtime.h>

typedef __attribute__((ext_vector_type(8))) short bf16x8;
typedef __attribute__((ext_vector_type(4))) float f32x4;
typedef __attribute__((ext_vector_type(4))) short s16x4;

__device__ __forceinline__ unsigned short f2bf(float f) {
    unsigned int u = __builtin_bit_cast(unsigned int, f);
    u += 0x7fffu + ((u >> 16) & 1u);   // round-to-nearest-even
    return (unsigned short)(u >> 16);
}
__device__ __forceinline__ float bf2f(unsigned short h) {
    return __builtin_bit_cast(float, ((unsigned int)h) << 16);
}

// Kernel 1: A[i][j] = (i==j) ? 0 : sum_d w[i, field[j], d] * w[j, field[i], d]
// (symmetric), stored bf16 in MFMA B-operand fragment order:
// apk[((kt*8+nt)*64 + lane)*8 + r]  <->  A[kt*32 + (lane>>4)*8 + r][nt*16 + (lane&15)]
__global__ void build_A_kernel(const float* __restrict__ w, const int* __restrict__ field,
                               unsigned short* __restrict__ apk) {
    int idx = blockIdx.x * 256 + threadIdx.x;   // 0..16383
    int i = idx >> 7, j = idx & 127;
    const float* wi = w + (i * 16 + field[j]) * 16;
    const float* wj = w + (j * 16 + field[i]) * 16;
    float s = 0.f;
#pragma unroll
    for (int d = 0; d < 16; ++d) s += wi[d] * wj[d];
    if (i == j) s = 0.f;
    int kt = i >> 5, g = (i >> 3) & 3, r = i & 7;
    int nt = j >> 4, c = j & 15;
    apk[((kt * 8 + nt) * 64 + (g * 16 + c)) * 8 + r] = f2bf(s);
}

// Main kernel: per 64-row tile, Y = X*A via mfma_f32_16x16x32_bf16,
// out[m] = 0.5 * sum_j X[m][j] * Y[m][j]
__global__ __launch_bounds__(256, 2)
void ffm_kernel(const float* __restrict__ x, const unsigned short* __restrict__ apk,
                float* __restrict__ out, int nTiles, int tilesPerWG) {
    __shared__ __align__(16) unsigned short Xl[2][64 * 128];  // 2 x 16 KiB, bf16, swizzled
    const int tid  = threadIdx.x;
    const int lane = tid & 63;
    const int wv   = tid >> 6;     // wave 0..3, owns rows [wv*16, wv*16+16)
    const int g    = lane >> 4;    // k-group (operands) / row-group (C/D)
    const int c    = lane & 15;    // row (A-op) / col (B-op, C/D)

    // Cache the whole interaction matrix as B-fragments in registers (128 VGPR).
    bf16x8 bfrag[4][8];
#pragma unroll
    for (int kt = 0; kt < 4; ++kt)
#pragma unroll
        for (int nt = 0; nt < 8; ++nt)
            bfrag[kt][nt] = *reinterpret_cast<const bf16x8*>(apk + ((kt * 8 + nt) * 64 + lane) * 8);

    const int tile0 = blockIdx.x * tilesPerWG;
    if (tile0 >= nTiles) return;

    // Prefetch first tile: 8 x float4 per thread, fully coalesced.
    float4 xr[8];
    {
        const float4* src = reinterpret_cast<const float4*>(x) + (size_t)tile0 * 2048;
#pragma unroll
        for (int i = 0; i < 8; ++i) xr[i] = src[i * 256 + tid];
    }

    int buf = 0;
    for (int t = 0; t < tilesPerWG; ++t) {
        int tile = tile0 + t;
        if (tile >= nTiles) break;

        // Stage regs -> LDS as bf16 with XOR swizzle (short idx ^= (row&7)<<3).
#pragma unroll
        for (int i = 0; i < 8; ++i) {
            int row = i * 8 + (tid >> 5);
            int k   = (tid & 31) * 4;
            int sw  = row * 128 + (k ^ ((row & 7) << 3));
            s16x4 s4;
            s4.x = (short)f2bf(xr[i].x);
            s4.y = (short)f2bf(xr[i].y);
            s4.z = (short)f2bf(xr[i].z);
            s4.w = (short)f2bf(xr[i].w);
            *reinterpret_cast<s16x4*>(&Xl[buf][sw]) = s4;
        }
        __syncthreads();

        // Prefetch next tile while computing this one.
        if (t + 1 < tilesPerWG && tile + 1 < nTiles) {
            const float4* src = reinterpret_cast<const float4*>(x) + (size_t)(tile + 1) * 2048;
#pragma unroll
            for (int i = 0; i < 8; ++i) xr[i] = src[i * 256 + tid];
        }

        // MFMA: Y(16x128) = X(16x128) * A(128x128), K in 4 steps of 32.
        f32x4 acc[8];
#pragma unroll
        for (int nt = 0; nt < 8; ++nt) acc[nt] = (f32x4){0.f, 0.f, 0.f, 0.f};
        const int m0 = wv * 16;
#pragma unroll
        for (int kt = 0; kt < 4; ++kt) {
            int row = m0 + c;                       // A-operand: row = lane&15
            int k0  = kt * 32 + g * 8;              // k-slots = (lane>>4)*8 + r
            bf16x8 xa = *reinterpret_cast<const bf16x8*>(
                &Xl[buf][row * 128 + (k0 ^ ((row & 7) << 3))]);
#pragma unroll
            for (int nt = 0; nt < 8; ++nt)
                acc[nt] = __builtin_amdgcn_mfma_f32_16x16x32_bf16(xa, bfrag[kt][nt], acc[nt], 0, 0, 0);
        }

        // Epilogue: out[m] = 0.5 * sum_j X[m][j]*Y[m][j].
        // C/D layout (measured): col = lane&15, row = (lane>>4)*4 + reg.
        float sacc[4] = {0.f, 0.f, 0.f, 0.f};
#pragma unroll
        for (int r = 0; r < 4; ++r) {
            int row  = m0 + g * 4 + r;
            int base = row * 128;
            int xv   = (row & 7) << 3;
#pragma unroll
            for (int nt = 0; nt < 8; ++nt) {
                int j = nt * 16 + c;
                sacc[r] += bf2f(Xl[buf][base + (j ^ xv)]) * acc[nt][r];
            }
        }
        // Reduce over the 16 col-lanes within each row-group.
#pragma unroll
        for (int m = 1; m < 16; m <<= 1)
#pragma unroll
            for (int r = 0; r < 4; ++r) sacc[r] += __shfl_xor(sacc[r], m, 64);

        if (c == 0) {
            float* o = out + (size_t)tile * 64 + wv * 16 + g * 4;
#pragma unroll
            for (int r = 0; r < 4; ++r) o[r] = 0.5f * sacc[r];
        }
        // One barrier per iteration + 2 buffers is sufficient:
        // a wave can only reach write(t+2) (same buffer) after bar(t+1),
        // and every wave's compute(t) precedes its write(t+1) in program order.
        buf ^= 1;
    }
}

extern "C" void kernel_launch(void* const* d_in, const int* in_sizes, int n_in,
                              void* d_out, int out_size, void* d_ws, size_t ws_size,
                              hipStream_t stream) {
    const float* x     = (const float*)d_in[0];
    const float* w     = (const float*)d_in[1];
    const int*   field = (const int*)d_in[2];
    float* outp        = (float*)d_out;
    unsigned short* apk = (unsigned short*)d_ws;   // 32 KiB packed A

    int B = in_sizes[0] / 128;
    build_A_kernel<<<64, 256, 0, stream>>>(w, field, apk);

    int nTiles = B / 64;               // 2048 for B=131072
    const int TPW = 2;                 // tiles per workgroup
    int grid = (nTiles + TPW - 1) / TPW;
    ffm_kernel<<<grid, 256, 0, stream>>>(x, apk, outp, nTiles, TPW);
}

// Round 3
// 21.335 us; speedup vs baseline: 1.3193x; 1.3193x over previous
//
#include <hip/hip_runtime.h>

typedef __attribute__((ext_vector_type(8))) short bf16x8;
typedef __attribute__((ext_vector_type(4))) float f32x4;
typedef __attribute__((ext_vector_type(4))) short s16x4;

__device__ __forceinline__ unsigned short f2bf(float f) {
    unsigned int u = __builtin_bit_cast(unsigned int, f);
    u += 0x7fffu + ((u >> 16) & 1u);   // round-to-nearest-even
    return (unsigned short)(u >> 16);
}
__device__ __forceinline__ float bf2f(unsigned short h) {
    return __builtin_bit_cast(float, ((unsigned int)h) << 16);
}

// Kernel 1: A[i][j] = (i==j) ? 0 : sum_d w[i, field[j], d] * w[j, field[i], d]
// Symmetric AND bit-identical across the diagonal (same products, same order),
// stored bf16 in MFMA fragment order:
// apk[((kt*8+nt)*64 + lane)*8 + r]  <->  A[kt*32 + (lane>>4)*8 + r][nt*16 + (lane&15)]
// By symmetry this same packing serves as the A-operand fragment for
// output-row-block nt with k-block kt.
__global__ void build_A_kernel(const float* __restrict__ w, const int* __restrict__ field,
                               unsigned short* __restrict__ apk) {
    int idx = blockIdx.x * 128 + threadIdx.x;   // 0..16383
    int i = idx >> 7, j = idx & 127;
    const float* wi = w + (i * 16 + field[j]) * 16;
    const float* wj = w + (j * 16 + field[i]) * 16;
    float s = 0.f;
#pragma unroll
    for (int d = 0; d < 16; ++d) s += wi[d] * wj[d];
    if (i == j) s = 0.f;
    int kt = i >> 5, g = (i >> 3) & 3, r = i & 7;
    int nt = j >> 4, c = j & 15;
    apk[((kt * 8 + nt) * 64 + (g * 16 + c)) * 8 + r] = f2bf(s);
}

// Main kernel: per 64-row tile, Yt = A * X^T via mfma_f32_16x16x32_bf16
// (A-operand = bfrag via symmetry), out[m] = 0.5 * sum_i X[m][i] * Y[m][i].
__global__ __launch_bounds__(256, 2)
void ffm_kernel(const float* __restrict__ x, const unsigned short* __restrict__ apk,
                float* __restrict__ out, int nTiles, int tilesPerWG) {
    __shared__ __align__(16) unsigned short Xl[2][64 * 128];  // 2 x 16 KiB, bf16, swizzled
    const int tid  = threadIdx.x;
    const int lane = tid & 63;
    const int wv   = tid >> 6;     // wave 0..3, owns rows [wv*16, wv*16+16)
    const int g    = lane >> 4;
    const int c    = lane & 15;

    // Cache the whole interaction matrix as MFMA fragments in registers (128 VGPR).
    bf16x8 bfrag[4][8];
#pragma unroll
    for (int kt = 0; kt < 4; ++kt)
#pragma unroll
        for (int nt = 0; nt < 8; ++nt)
            bfrag[kt][nt] = *reinterpret_cast<const bf16x8*>(apk + ((kt * 8 + nt) * 64 + lane) * 8);

    const int tile0 = blockIdx.x * tilesPerWG;
    if (tile0 >= nTiles) return;

    // Prefetch first tile: 8 x 16B per thread, fully coalesced, nontemporal.
    f32x4 xr[8];
    {
        const f32x4* src = reinterpret_cast<const f32x4*>(x) + (size_t)tile0 * 2048;
#pragma unroll
        for (int i = 0; i < 8; ++i) xr[i] = __builtin_nontemporal_load(&src[i * 256 + tid]);
    }

    int buf = 0;
    for (int t = 0; t < tilesPerWG; ++t) {
        int tile = tile0 + t;
        if (tile >= nTiles) break;

        // Stage regs -> LDS as bf16 with XOR swizzle (short idx ^= (row&7)<<3).
#pragma unroll
        for (int i = 0; i < 8; ++i) {
            int row = i * 8 + (tid >> 5);
            int k   = (tid & 31) * 4;
            int sw  = row * 128 + (k ^ ((row & 7) << 3));
            s16x4 s4;
            s4.x = (short)f2bf(xr[i][0]);
            s4.y = (short)f2bf(xr[i][1]);
            s4.z = (short)f2bf(xr[i][2]);
            s4.w = (short)f2bf(xr[i][3]);
            *reinterpret_cast<s16x4*>(&Xl[buf][sw]) = s4;
        }

        // Issue next-tile prefetch BEFORE the barrier (overlaps barrier + compute).
        if (t + 1 < tilesPerWG && tile + 1 < nTiles) {
            const f32x4* src = reinterpret_cast<const f32x4*>(x) + (size_t)(tile + 1) * 2048;
#pragma unroll
            for (int i = 0; i < 8; ++i) xr[i] = __builtin_nontemporal_load(&src[i * 256 + tid]);
        }
        __syncthreads();

        // Yt = A(128x128) * X^T(128x16): for each output row-block q,
        // acc[q] holds Y[m0+c][q*16 + g*4 + r] (C/D: col=lane&15 -> m, row -> i).
        // A-operand fragment for (q,kt) == bfrag[kt][q] by symmetry of A.
        f32x4 acc[8];
#pragma unroll
        for (int q = 0; q < 8; ++q) acc[q] = (f32x4){0.f, 0.f, 0.f, 0.f};
        const int m0 = wv * 16;
        const int rowbase = (m0 + c) * 128;
        const int xv = ((m0 + c) & 7) << 3;
#pragma unroll
        for (int kt = 0; kt < 4; ++kt) {
            int k0 = kt * 32 + g * 8;   // B-operand: col=c (-> row m0+c), k-slots g*8+r
            bf16x8 xa = *reinterpret_cast<const bf16x8*>(
                &Xl[buf][rowbase + (k0 ^ xv)]);
#pragma unroll
            for (int q = 0; q < 8; ++q)
                acc[q] = __builtin_amdgcn_mfma_f32_16x16x32_bf16(bfrag[kt][q], xa, acc[q], 0, 0, 0);
        }

        // Epilogue: sacc = sum over this lane's 32 i-values of X[m][i]*Y[m][i],
        // X read as 4 contiguous bf16 per q (one ds_read_b64 each).
        float sacc = 0.f;
#pragma unroll
        for (int q = 0; q < 8; ++q) {
            int ix = q * 16 + g * 4;
            s16x4 xs = *reinterpret_cast<const s16x4*>(&Xl[buf][rowbase + (ix ^ xv)]);
            sacc += bf2f((unsigned short)xs.x) * acc[q][0];
            sacc += bf2f((unsigned short)xs.y) * acc[q][1];
            sacc += bf2f((unsigned short)xs.z) * acc[q][2];
            sacc += bf2f((unsigned short)xs.w) * acc[q][3];
        }
        // Reduce across the 4 g-groups (lanes sharing c).
        sacc += __shfl_xor(sacc, 16, 64);
        sacc += __shfl_xor(sacc, 32, 64);
        if (g == 0) out[(size_t)tile * 64 + m0 + c] = 0.5f * sacc;

        buf ^= 1;
    }
}

extern "C" void kernel_launch(void* const* d_in, const int* in_sizes, int n_in,
                              void* d_out, int out_size, void* d_ws, size_t ws_size,
                              hipStream_t stream) {
    const float* x     = (const float*)d_in[0];
    const float* w     = (const float*)d_in[1];
    const int*   field = (const int*)d_in[2];
    float* outp        = (float*)d_out;
    unsigned short* apk = (unsigned short*)d_ws;   // 32 KiB packed A

    int B = in_sizes[0] / 128;
    build_A_kernel<<<128, 128, 0, stream>>>(w, field, apk);

    int nTiles = B / 64;               // 2048 for B=131072
    const int TPW = 4;                 // tiles per workgroup
    int grid = (nTiles + TPW - 1) / TPW;   // 512 = exactly 2 blocks/CU
    ffm_kernel<<<grid, 256, 0, stream>>>(x, apk, outp, nTiles, TPW);
}